// Round 21
// baseline (95.007 us; speedup 1.0000x reference)
//
#include <hip/hip_runtime.h>

#define NBATCH  131072
#define THREADS 256            // 4 waves, p-split over the same 16 batches
#define BPB     16
#define NBLOCKS (NBATCH / BPB)     // 8192

typedef __attribute__((ext_vector_type(8))) _Float16 half8;
typedef __attribute__((ext_vector_type(4))) float f32x4;

// LDS (bytes): sxT f16 [16 b][15 p][80B: 64B = ch 0..31 (21 data + 11 zero), 16B pad]
//              conv0 writes y in place; stage3 reuses [0,14080) as out f32 [16][220]
//  [19200, 20480):  lbuf f32 [16][20]  logit exchange
#define Y_RS 80
#define Y_BS 1200
#define LB_OFF 19200
#define SMEM_BYTES 20480
#define OUT_SDW 220

// d_ws layout (bytes):
#define WF1_OFF 2048
#define WF2_OFF 14336
#define SH1_OFF 26624
#define SH2_OFF 26880
#define WFA_OFF 27008      // att logit A-fragment: uint4[64]
#define ATTB_OFF 28032     // padded attb: f32[16]

static __device__ __forceinline__ unsigned int pkrtz(float a, float b) {
    __fp16 __attribute__((ext_vector_type(2))) h =
        __builtin_amdgcn_cvt_pkrtz(a, b);                     // 1 VALU op, RTZ
    return __builtin_bit_cast(unsigned int, h);
}
static __device__ __forceinline__ half8 splat8(float s) {
    const _Float16 h = (_Float16)s;
    half8 v;
    #pragma unroll
    for (int j = 0; j < 8; ++j) v[j] = h;
    return v;
}

// ============ prep kernel (4 waves, work split): fold BN, pack fragments ============
__global__ __launch_bounds__(256, 1)
void peptide_prep(const float* __restrict__ w0,
                  const float* __restrict__ attw, const float* __restrict__ attb,
                  const float* __restrict__ w1, const float* __restrict__ cb1,
                  const float* __restrict__ g1, const float* __restrict__ bt1,
                  const float* __restrict__ mn1, const float* __restrict__ vr1,
                  const float* __restrict__ w2, const float* __restrict__ cb2,
                  const float* __restrict__ g2, const float* __restrict__ bt2,
                  const float* __restrict__ mn2, const float* __restrict__ vr2,
                  char* __restrict__ ws)
{
    const int tid  = threadIdx.x;
    const int lane = tid & 63;
    const int wv   = tid >> 6;
    const int col = lane & 15, g = lane >> 4;
    uint4* wf0 = (uint4*)ws;
    uint4* wf1 = (uint4*)(ws + WF1_OFF);
    uint4* wf2 = (uint4*)(ws + WF2_OFF);
    float* sh1 = (float*)(ws + SH1_OFF);
    float* sh2 = (float*)(ws + SH2_OFF);

    if (wv == 0) {
        // conv0 fragments, chan0(mt,row) = 8*(row>>2) + 4*mt + (row&3)
        #pragma unroll
        for (int mt = 0; mt < 2; ++mt) {
            const int oc = 8*(col>>2) + 4*mt + (col&3);
            half8 fh;
            #pragma unroll
            for (int j = 0; j < 8; ++j) {
                const int c = 8 * g + j;
                fh[j] = (c < 21) ? (_Float16)w0[oc * 21 + c] : (_Float16)0.f;
            }
            wf0[mt * 64 + lane] = __builtin_bit_cast(uint4, fh);
        }
        // att logit A-fragment: row = position, k = channel
        {
            half8 fh;
            #pragma unroll
            for (int j = 0; j < 8; ++j)
                fh[j] = (col < 15) ? (_Float16)attw[col * 32 + 8 * g + j]
                                   : (_Float16)0.f;
            ((uint4*)(ws + WFA_OFF))[lane] = __builtin_bit_cast(uint4, fh);
        }
        if (lane < 16)
            ((float*)(ws + ATTB_OFF))[lane] = (lane < 15) ? attb[lane] : 0.f;
        // shift vectors (per g)
        if (col == 0) {
            #pragma unroll
            for (int k = 0; k < 16; ++k) {
                const int H = k >> 3, t = (k >> 2) & 1, r = k & 3;
                const int o = 32*H + 8*g + 4*t + r;
                const float iva = g1[o] * rsqrtf(vr1[o] + 1e-5f);
                sh1[g*16 + k] = bt1[o] + (cb1[o] - mn1[o]) * iva;
            }
            #pragma unroll
            for (int k = 0; k < 8; ++k) {
                const int MT = k >> 2, r = k & 3;
                const int oc = MT*16 + 4*g + r;
                if (oc < 20) {
                    const float iva = g2[oc] * rsqrtf(vr2[oc] + 1e-5f);
                    sh2[g*8 + k] = bt2[oc] + (cb2[oc] - mn2[oc]) * iva;
                } else sh2[g*8 + k] = 0.f;
            }
        }
    } else if (wv < 3) {
        // conv1 fragments, half H = wv-1; chan1 = 32H + 8(col>>2) + 4t + (col&3)
        const int H = wv - 1;
        #pragma unroll
        for (int t = 0; t < 2; ++t) {
            const int o = 32*H + 8*(col>>2) + 4*t + (col&3);
            const float iva = g1[o] * rsqrtf(vr1[o] + 1e-5f);
            #pragma unroll
            for (int s = 0; s < 3; ++s) {
                half8 fh;
                #pragma unroll
                for (int j = 0; j < 8; ++j)
                    fh[j] = (_Float16)(w1[o*96 + g*24 + j*3 + s] * iva);
                wf1[((H*2 + t)*3 + s)*64 + lane] = __builtin_bit_cast(uint4, fh);
            }
        }
    } else {
        // conv2 fragments, bn2 folded, zero for o >= 20
        #pragma unroll
        for (int MT = 0; MT < 2; ++MT) {
            const int o = MT * 16 + col;
            const float iva = (o < 20) ? g2[o] * rsqrtf(vr2[o] + 1e-5f) : 0.f;
            #pragma unroll
            for (int hh = 0; hh < 2; ++hh)
            #pragma unroll
            for (int tap = 0; tap < 3; ++tap) {
                half8 fh;
                #pragma unroll
                for (int j = 0; j < 8; ++j)
                    fh[j] = (o < 20) ? (_Float16)(w2[o*192 + hh*96 + g*24 + j*3 + tap] * iva)
                                     : (_Float16)0.f;
                wf2[((MT*2 + hh)*3 + tap)*64 + lane] = __builtin_bit_cast(uint4, fh);
            }
        }
    }
}

// ---- conv0 via MFMA + logit-MFMA + softmax; h packed f16; y in-place to sxT ----
template<int P0, int NP>
__device__ __forceinline__ void conv0_att(char* sxT, float* lbuf,
        const half8 (&af0)[2], const half8 af_att, const float4 attb4,
        int col, int g, int lane) {
    half8 hq[NP];                      // packed h: channels 8g..8g+7 (permuted rows)
    #pragma unroll
    for (int i = 0; i < NP; ++i) {
        const int p = P0 + i;
        half8 bf = *(const half8*)(sxT + col * Y_BS + p * Y_RS + g * 16);
        const f32x4 z = {0.f, 0.f, 0.f, 0.f};
        f32x4 h0 = __builtin_amdgcn_mfma_f32_16x16x32_f16(af0[0], bf, z, 0, 0, 0);
        f32x4 h1 = __builtin_amdgcn_mfma_f32_16x16x32_f16(af0[1], bf, z, 0, 0, 0);
        uint4 u;
        u.x = pkrtz(h0[0], h0[1]); u.y = pkrtz(h0[2], h0[3]);
        u.z = pkrtz(h1[0], h1[1]); u.w = pkrtz(h1[2], h1[3]);
        hq[i] = __builtin_bit_cast(half8, u);
        // logits for all batches via MFMA: C[row=pos][col=batch], acc-init = attb
        f32x4 al = {attb4.x, attb4.y, attb4.z, attb4.w};
        al = __builtin_amdgcn_mfma_f32_16x16x32_f16(af_att, hq[i], al, 0, 0, 0);
        if (g == (p >> 2)) lbuf[col * 20 + p] = al[p & 3];
    }
    __syncthreads();    // all 15 logits visible; all conv0 x-reads complete
    const float* lb = lbuf + col * 20;
    float4 l0 = *(const float4*)(lb + 0);
    float4 l1 = *(const float4*)(lb + 4);
    float4 l2 = *(const float4*)(lb + 8);
    float4 l3 = *(const float4*)(lb + 12);      // .w garbage, unused
    float lg[15] = {l0.x,l0.y,l0.z,l0.w, l1.x,l1.y,l1.z,l1.w,
                    l2.x,l2.y,l2.z,l2.w, l3.x,l3.y,l3.z};
    float mA = fmaxf(fmaxf(fmaxf(lg[0],lg[1]), fmaxf(lg[2],lg[3])),
                     fmaxf(fmaxf(lg[4],lg[5]), fmaxf(lg[6],lg[7])));
    float mB = fmaxf(fmaxf(fmaxf(lg[8],lg[9]), fmaxf(lg[10],lg[11])),
                     fmaxf(fmaxf(lg[12],lg[13]), lg[14]));
    const float mx = fmaxf(mA, mB);
    float e[15];
    #pragma unroll
    for (int l = 0; l < 15; ++l) e[l] = __expf(lg[l] - mx);
    float sA = ((e[0]+e[1]) + (e[2]+e[3])) + ((e[4]+e[5]) + (e[6]+e[7]));
    float sB = ((e[8]+e[9]) + (e[10]+e[11])) + ((e[12]+e[13]) + e[14]);
    const float inv = 1.f / (sA + sB);
    #pragma unroll
    for (int i = 0; i < NP; ++i) {
        const int p = P0 + i;
        half8 ys = hq[i] * splat8(e[p] * inv);   // v_pk_mul_f16
        *(uint4*)(sxT + col * Y_BS + p * Y_RS + 16 * g) =
            __builtin_bit_cast(uint4, ys);       // single contiguous b128 write
    }
}

// ---- conv1 half-sweep H from prefolded fragments + register y rows -> frH ----
template<int H, int NR, int NY>
__device__ __forceinline__ void conv1_half(
    const half8 (&yrow)[NY], half8 (&frH)[NR], const half8 h001,
    const int lane, const int g, const char* __restrict__ ws)
{
    const uint4* wf1 = (const uint4*)(ws + WF1_OFF);
    half8 afA[3], afB[3];
    #pragma unroll
    for (int s = 0; s < 3; ++s) {
        afA[s] = __builtin_bit_cast(half8, wf1[((H*2 + 0)*3 + s)*64 + lane]);
        afB[s] = __builtin_bit_cast(half8, wf1[((H*2 + 1)*3 + s)*64 + lane]);
    }
    const float* sh1 = (const float*)(ws + SH1_OFF) + g*16 + H*8;
    float4 shv0 = *(const float4*)(sh1);
    float4 shv1 = *(const float4*)(sh1 + 4);

    #pragma unroll
    for (int i = 0; i < NR; ++i) {
        f32x4 a0 = {shv0.x, shv0.y, shv0.z, shv0.w};   // acc-init = bn1 shifts
        f32x4 a1 = {shv1.x, shv1.y, shv1.z, shv1.w};
        #pragma unroll
        for (int s = 0; s < 3; ++s) {
            const half8 yy = yrow[i + s];
            a0 = __builtin_amdgcn_mfma_f32_16x16x32_f16(afA[s], yy, a0, 0,0,0);
            a1 = __builtin_amdgcn_mfma_f32_16x16x32_f16(afB[s], yy, a1, 0,0,0);
        }
        // pack first, then LeakyReLU in packed f16 (pk_mul + pk_max)
        uint4 u;
        u.x = pkrtz(a0[0], a0[1]); u.y = pkrtz(a0[2], a0[3]);
        u.z = pkrtz(a1[0], a1[1]); u.w = pkrtz(a1[2], a1[3]);
        half8 v = __builtin_bit_cast(half8, u);
        frH[i] = __builtin_elementwise_max(v, v * h001);
    }
}

// ---- conv2 tile MT from prefolded fragments -> LDS out staging ----
template<int MT, int P0, int NP, int NR>
__device__ __forceinline__ void conv2_tile(
    float* __restrict__ sout, const half8 (&fr0)[NR], const half8 (&fr1)[NR],
    const int col, const int g, const int lane, const char* __restrict__ ws)
{
    const uint4* wf2 = (const uint4*)(ws + WF2_OFF);
    half8 af3[6];
    #pragma unroll
    for (int hh = 0; hh < 2; ++hh)
    #pragma unroll
    for (int tap = 0; tap < 3; ++tap)
        af3[tap*2 + hh] = __builtin_bit_cast(half8, wf2[((MT*2 + hh)*3 + tap)*64 + lane]);
    float4 shv = *(const float4*)((const float*)(ws + SH2_OFF) + g*8 + MT*4);

    #pragma unroll
    for (int pp = 0; pp < NP; ++pp) {
        const int p = P0 + pp;
        f32x4 acc = {shv.x, shv.y, shv.z, shv.w};   // acc-init = bn2 shifts
        #pragma unroll
        for (int s = 0; s < 6; ++s) {
            const half8 bb = (s & 1) ? fr1[pp + (s >> 1)] : fr0[pp + (s >> 1)];
            acc = __builtin_amdgcn_mfma_f32_16x16x32_f16(af3[s], bb, acc, 0,0,0);
        }
        #pragma unroll
        for (int r = 0; r < 4; ++r) {
            const int oc = MT*16 + 4*g + r;
            if (oc < 20) {
                float t0 = fmaxf(acc[r], 0.01f * acc[r]);
                sout[col*OUT_SDW + oc*11 + p] = t0;
            }
        }
    }
}

// ---- conv1 (shared y rows, two half-sweeps) -> conv2 (two tile-sweeps) ----
template<int R0, int NR, int P0, int NP>
__device__ __forceinline__ void stack23(
    char* __restrict__ sxT, const int col, const int g, const int lane,
    const char* __restrict__ ws)
{
    float* sout = (float*)sxT;
    const char* yb = sxT + col * Y_BS;
    const half8 h001 = splat8(0.01f);
    // read the NR+2 y rows ONCE; both conv1 halves consume from registers
    half8 yrow[NR + 2];
    #pragma unroll
    for (int i = 0; i < NR + 2; ++i)
        yrow[i] = *(const half8*)(yb + (R0 + i) * Y_RS + g * 16);

    half8 fr0[NR], fr1[NR];
    conv1_half<0, NR, NR+2>(yrow, fr0, h001, lane, g, ws);
    __builtin_amdgcn_sched_barrier(0);    // keep the two halves' af live-ranges separate
    conv1_half<1, NR, NR+2>(yrow, fr1, h001, lane, g, ws);
    __syncthreads();   // all y reads done before out staging overwrites sxT
    conv2_tile<0, P0, NP, NR>(sout, fr0, fr1, col, g, lane, ws);
    __builtin_amdgcn_sched_barrier(0);
    conv2_tile<1, P0, NP, NR>(sout, fr0, fr1, col, g, lane, ws);
}

__global__ __launch_bounds__(THREADS, 2)
void peptide_v21(const float* __restrict__ x,
                 const char*  __restrict__ ws,     // prefolded fragments
                 float* __restrict__ out)          // [B][20][11]
{
    __shared__ __align__(16) char smem[SMEM_BYTES];
    char* sxT = smem;
    float* lbuf = (float*)(smem + LB_OFF);

    const int tid  = threadIdx.x;
    const int lane = tid & 63;
    const int wv   = tid >> 6;      // 0..3
    const int col  = lane & 15;
    const int g    = lane >> 4;

    // ---- quad-gather transpose: 192 tasks over 256 threads (single pass) ----
    {
        const float* xg = x + (size_t)blockIdx.x * (BPB * 315);
        const int u = tid;
        if (u < 192) {
            const int b2 = u & 15;
            const int qd = (u >> 4) & 3;
            const int ch = u >> 6;               // 0,1,2 (wave-uniform)
            const int po = (qd == 3) ? 11 : 4 * qd;
            const float* src = xg + b2 * 315 + po;
            char* dstb = sxT + b2 * Y_BS + ch * 16;
            if (ch < 2) {
                f32x4 v4[8];
                #pragma unroll
                for (int j = 0; j < 8; ++j)
                    v4[j] = *(const f32x4*)(src + (ch * 8 + j) * 15);
                #pragma unroll
                for (int e = 0; e < 4; ++e) {
                    if (qd < 3 || e > 0) {
                        const int p = po + e;
                        uint4 d;
                        d.x = pkrtz(v4[0][e], v4[1][e]);
                        d.y = pkrtz(v4[2][e], v4[3][e]);
                        d.z = pkrtz(v4[4][e], v4[5][e]);
                        d.w = pkrtz(v4[6][e], v4[7][e]);
                        *(uint4*)(dstb + p * Y_RS) = d;
                    }
                }
            } else {
                f32x4 v4[5];
                #pragma unroll
                for (int j = 0; j < 5; ++j)
                    v4[j] = *(const f32x4*)(src + (16 + j) * 15);
                const uint4 zz = {0u, 0u, 0u, 0u};
                #pragma unroll
                for (int e = 0; e < 4; ++e) {
                    if (qd < 3 || e > 0) {
                        const int p = po + e;
                        uint4 d;
                        d.x = pkrtz(v4[0][e], v4[1][e]);
                        d.y = pkrtz(v4[2][e], v4[3][e]);
                        d.z = pkrtz(v4[4][e], 0.f);
                        d.w = 0u;
                        *(uint4*)(dstb + p * Y_RS) = d;        // ch 16..23
                        *(uint4*)(dstb + p * Y_RS + 16) = zz;  // ch 24..31
                    }
                }
            }
        }
    }

    // fragments from d_ws
    half8 af0[2], af_att;
    float4 attb4;
    {
        const uint4* wf0 = (const uint4*)ws;
        af0[0] = __builtin_bit_cast(half8, wf0[lane]);
        af0[1] = __builtin_bit_cast(half8, wf0[64 + lane]);
        af_att = __builtin_bit_cast(half8, ((const uint4*)(ws + WFA_OFF))[lane]);
        attb4  = *(const float4*)((const float*)(ws + ATTB_OFF) + 4 * g);
    }
    __syncthreads();                      // xT ready

    // ---- conv0 MFMA + logit-MFMA + softmax (y in-place); p-split 4/4/4/3 ----
    if      (wv == 0) conv0_att<0,  4>(sxT, lbuf, af0, af_att, attb4, col, g, lane);
    else if (wv == 1) conv0_att<4,  4>(sxT, lbuf, af0, af_att, attb4, col, g, lane);
    else if (wv == 2) conv0_att<8,  4>(sxT, lbuf, af0, af_att, attb4, col, g, lane);
    else              conv0_att<12, 3>(sxT, lbuf, af0, af_att, attb4, col, g, lane);
    __syncthreads();                      // y complete (cross-wave rows)

    // ---- conv1 -> regs -> conv2 -> out staging; p-split 3/3/3/2 (seam rows redone) ----
    if      (wv == 0) stack23<0, 5, 0, 3>(sxT, col, g, lane, ws);
    else if (wv == 1) stack23<3, 5, 3, 3>(sxT, col, g, lane, ws);
    else if (wv == 2) stack23<6, 5, 6, 3>(sxT, col, g, lane, ws);
    else              stack23<9, 4, 9, 2>(sxT, col, g, lane, ws);
    __syncthreads();                      // out staging complete

    // ---- gap-free coalesced copy-out: 16 x 220 dw = one 14080 B span ----
    {
        float* ob = out + (size_t)blockIdx.x * (BPB * 220);
        const float* sf = (const float*)sxT;
        #pragma unroll
        for (int j = 0; j < 4; ++j) {
            const int u = j * THREADS + tid;          // 16B unit
            if (u < 880) {
                f32x4 v = *(const f32x4*)(sf + u * 4);
                *(f32x4*)(ob + u * 4) = v;
            }
        }
    }
}

extern "C" void kernel_launch(void* const* d_in, const int* in_sizes, int n_in,
                              void* d_out, int out_size, void* d_ws, size_t ws_size,
                              hipStream_t stream) {
    const float* x    = (const float*)d_in[0];
    const float* w0   = (const float*)d_in[1];
    const float* attw = (const float*)d_in[2];
    const float* attb = (const float*)d_in[3];
    const float* w1   = (const float*)d_in[4];
    const float* cb1  = (const float*)d_in[5];
    const float* g1   = (const float*)d_in[6];
    const float* bt1  = (const float*)d_in[7];
    const float* mn1  = (const float*)d_in[8];
    const float* vr1  = (const float*)d_in[9];
    const float* w2   = (const float*)d_in[10];
    const float* cb2  = (const float*)d_in[11];
    const float* g2   = (const float*)d_in[12];
    const float* bt2  = (const float*)d_in[13];
    const float* mn2  = (const float*)d_in[14];
    const float* vr2  = (const float*)d_in[15];

    hipLaunchKernelGGL(peptide_prep, dim3(1), dim3(256), 0, stream,
                       w0, attw, attb, w1, cb1, g1, bt1, mn1, vr1,
                       w2, cb2, g2, bt2, mn2, vr2, (char*)d_ws);
    hipLaunchKernelGGL(peptide_v21, dim3(NBLOCKS), dim3(THREADS), 0, stream,
                       x, (const char*)d_ws, (float*)d_out);
}

// Round 22
// 80.448 us; speedup vs baseline: 1.1810x; 1.1810x over previous
//
#include <hip/hip_runtime.h>

#define NBATCH  131072
#define THREADS 128
#define BPB     16
#define NBLOCKS (NBATCH / BPB)     // 8192

typedef __attribute__((ext_vector_type(8))) _Float16 half8;
typedef __attribute__((ext_vector_type(4))) float f32x4;

// LDS (bytes): sxT f16 [16 b][15 p][80B: 64B = ch 0..31 (21 data + 11 zero), 12B pad, 4B logit]
//              conv0 writes y in place; logits live in the row pads (+64);
//              stage3 reuses [0,14080) as out staging f32 [16][220]
#define Y_RS 80
#define Y_BS 1200
#define SMEM_BYTES 19200
#define OUT_SDW 220

// d_ws layout (bytes):
#define WF1_OFF 2048
#define WF2_OFF 14336
#define SH1_OFF 26624
#define SH2_OFF 26880
#define WFA_OFF 27008      // att logit A-fragment: uint4[64]
#define ATTB_OFF 28032     // padded attb: f32[16]

static __device__ __forceinline__ unsigned int pkrtz(float a, float b) {
    __fp16 __attribute__((ext_vector_type(2))) h =
        __builtin_amdgcn_cvt_pkrtz(a, b);                     // 1 VALU op, RTZ
    return __builtin_bit_cast(unsigned int, h);
}
static __device__ __forceinline__ half8 splat8(float s) {
    const _Float16 h = (_Float16)s;
    half8 v;
    #pragma unroll
    for (int j = 0; j < 8; ++j) v[j] = h;
    return v;
}

// ============ prep kernel (4 waves, work split): fold BN, pack fragments ============
__global__ __launch_bounds__(256, 1)
void peptide_prep(const float* __restrict__ w0,
                  const float* __restrict__ attw, const float* __restrict__ attb,
                  const float* __restrict__ w1, const float* __restrict__ cb1,
                  const float* __restrict__ g1, const float* __restrict__ bt1,
                  const float* __restrict__ mn1, const float* __restrict__ vr1,
                  const float* __restrict__ w2, const float* __restrict__ cb2,
                  const float* __restrict__ g2, const float* __restrict__ bt2,
                  const float* __restrict__ mn2, const float* __restrict__ vr2,
                  char* __restrict__ ws)
{
    const int tid  = threadIdx.x;
    const int lane = tid & 63;
    const int wv   = tid >> 6;
    const int col = lane & 15, g = lane >> 4;
    uint4* wf0 = (uint4*)ws;
    uint4* wf1 = (uint4*)(ws + WF1_OFF);
    uint4* wf2 = (uint4*)(ws + WF2_OFF);
    float* sh1 = (float*)(ws + SH1_OFF);
    float* sh2 = (float*)(ws + SH2_OFF);

    if (wv == 0) {
        // conv0 fragments, chan0(mt,row) = 8*(row>>2) + 4*mt + (row&3)
        #pragma unroll
        for (int mt = 0; mt < 2; ++mt) {
            const int oc = 8*(col>>2) + 4*mt + (col&3);
            half8 fh;
            #pragma unroll
            for (int j = 0; j < 8; ++j) {
                const int c = 8 * g + j;
                fh[j] = (c < 21) ? (_Float16)w0[oc * 21 + c] : (_Float16)0.f;
            }
            wf0[mt * 64 + lane] = __builtin_bit_cast(uint4, fh);
        }
        // att logit A-fragment: row = position, k = channel
        {
            half8 fh;
            #pragma unroll
            for (int j = 0; j < 8; ++j)
                fh[j] = (col < 15) ? (_Float16)attw[col * 32 + 8 * g + j]
                                   : (_Float16)0.f;
            ((uint4*)(ws + WFA_OFF))[lane] = __builtin_bit_cast(uint4, fh);
        }
        if (lane < 16)
            ((float*)(ws + ATTB_OFF))[lane] = (lane < 15) ? attb[lane] : 0.f;
        // shift vectors (per g)
        if (col == 0) {
            #pragma unroll
            for (int k = 0; k < 16; ++k) {
                const int H = k >> 3, t = (k >> 2) & 1, r = k & 3;
                const int o = 32*H + 8*g + 4*t + r;
                const float iva = g1[o] * rsqrtf(vr1[o] + 1e-5f);
                sh1[g*16 + k] = bt1[o] + (cb1[o] - mn1[o]) * iva;
            }
            #pragma unroll
            for (int k = 0; k < 8; ++k) {
                const int MT = k >> 2, r = k & 3;
                const int oc = MT*16 + 4*g + r;
                if (oc < 20) {
                    const float iva = g2[oc] * rsqrtf(vr2[oc] + 1e-5f);
                    sh2[g*8 + k] = bt2[oc] + (cb2[oc] - mn2[oc]) * iva;
                } else sh2[g*8 + k] = 0.f;
            }
        }
    } else if (wv < 3) {
        // conv1 fragments, half H = wv-1; chan1 = 32H + 8(col>>2) + 4t + (col&3)
        const int H = wv - 1;
        #pragma unroll
        for (int t = 0; t < 2; ++t) {
            const int o = 32*H + 8*(col>>2) + 4*t + (col&3);
            const float iva = g1[o] * rsqrtf(vr1[o] + 1e-5f);
            #pragma unroll
            for (int s = 0; s < 3; ++s) {
                half8 fh;
                #pragma unroll
                for (int j = 0; j < 8; ++j)
                    fh[j] = (_Float16)(w1[o*96 + g*24 + j*3 + s] * iva);
                wf1[((H*2 + t)*3 + s)*64 + lane] = __builtin_bit_cast(uint4, fh);
            }
        }
    } else {
        // conv2 fragments, bn2 folded, zero for o >= 20
        #pragma unroll
        for (int MT = 0; MT < 2; ++MT) {
            const int o = MT * 16 + col;
            const float iva = (o < 20) ? g2[o] * rsqrtf(vr2[o] + 1e-5f) : 0.f;
            #pragma unroll
            for (int hh = 0; hh < 2; ++hh)
            #pragma unroll
            for (int tap = 0; tap < 3; ++tap) {
                half8 fh;
                #pragma unroll
                for (int j = 0; j < 8; ++j)
                    fh[j] = (o < 20) ? (_Float16)(w2[o*192 + hh*96 + g*24 + j*3 + tap] * iva)
                                     : (_Float16)0.f;
                wf2[((MT*2 + hh)*3 + tap)*64 + lane] = __builtin_bit_cast(uint4, fh);
            }
        }
    }
}

// ---- conv0 via MFMA + logit-MFMA + softmax; h packed f16; y in-place; logits in pads ----
template<int P0, int NP>
__device__ __forceinline__ void conv0_att(char* sxT,
        const half8 (&af0)[2], const half8 af_att, const float4 attb4,
        int col, int g, int lane) {
    half8 hq[NP];                      // packed h: channels 8g..8g+7 (permuted rows)
    #pragma unroll
    for (int i = 0; i < NP; ++i) {
        const int p = P0 + i;
        half8 bf = *(const half8*)(sxT + col * Y_BS + p * Y_RS + g * 16);
        const f32x4 z = {0.f, 0.f, 0.f, 0.f};
        f32x4 h0 = __builtin_amdgcn_mfma_f32_16x16x32_f16(af0[0], bf, z, 0, 0, 0);
        f32x4 h1 = __builtin_amdgcn_mfma_f32_16x16x32_f16(af0[1], bf, z, 0, 0, 0);
        uint4 u;
        u.x = pkrtz(h0[0], h0[1]); u.y = pkrtz(h0[2], h0[3]);
        u.z = pkrtz(h1[0], h1[1]); u.w = pkrtz(h1[2], h1[3]);
        hq[i] = __builtin_bit_cast(half8, u);
        // logits for all batches via MFMA: C[row=pos][col=batch], acc-init = attb
        f32x4 al = {attb4.x, attb4.y, attb4.z, attb4.w};
        al = __builtin_amdgcn_mfma_f32_16x16x32_f16(af_att, hq[i], al, 0, 0, 0);
        if (g == (p >> 2))
            *(float*)(sxT + col * Y_BS + p * Y_RS + 64) = al[p & 3];  // row pad
    }
    __syncthreads();    // all 15 logits visible; all conv0 x-reads complete
    float lg[15];
    #pragma unroll
    for (int l = 0; l < 15; ++l)
        lg[l] = *(const float*)(sxT + col * Y_BS + l * Y_RS + 64);
    float mA = fmaxf(fmaxf(fmaxf(lg[0],lg[1]), fmaxf(lg[2],lg[3])),
                     fmaxf(fmaxf(lg[4],lg[5]), fmaxf(lg[6],lg[7])));
    float mB = fmaxf(fmaxf(fmaxf(lg[8],lg[9]), fmaxf(lg[10],lg[11])),
                     fmaxf(fmaxf(lg[12],lg[13]), lg[14]));
    const float mx = fmaxf(mA, mB);
    float e[15];
    #pragma unroll
    for (int l = 0; l < 15; ++l) e[l] = __expf(lg[l] - mx);
    float sA = ((e[0]+e[1]) + (e[2]+e[3])) + ((e[4]+e[5]) + (e[6]+e[7]));
    float sB = ((e[8]+e[9]) + (e[10]+e[11])) + ((e[12]+e[13]) + e[14]);
    const float inv = 1.f / (sA + sB);
    #pragma unroll
    for (int i = 0; i < NP; ++i) {
        const int p = P0 + i;
        half8 ys = hq[i] * splat8(e[p] * inv);   // v_pk_mul_f16
        *(uint4*)(sxT + col * Y_BS + p * Y_RS + 16 * g) =
            __builtin_bit_cast(uint4, ys);       // single contiguous b128 write
    }
}

// ---- conv1 half-sweep H from prefolded fragments -> frH register B-fragments ----
template<int H, int R0, int NR>
__device__ __forceinline__ void conv1_half(
    const char* __restrict__ yb, half8 (&frH)[NR],
    const int lane, const int g, const char* __restrict__ ws)
{
    const uint4* wf1 = (const uint4*)(ws + WF1_OFF);
    half8 afA[3], afB[3];
    #pragma unroll
    for (int s = 0; s < 3; ++s) {
        afA[s] = __builtin_bit_cast(half8, wf1[((H*2 + 0)*3 + s)*64 + lane]);
        afB[s] = __builtin_bit_cast(half8, wf1[((H*2 + 1)*3 + s)*64 + lane]);
    }
    const float* sh1 = (const float*)(ws + SH1_OFF) + g*16 + H*8;
    float4 shv0 = *(const float4*)(sh1);
    float4 shv1 = *(const float4*)(sh1 + 4);

    half8 y3[3];
    y3[(R0 + 0) % 3] = *(const half8*)(yb + (R0 + 0) * Y_RS + g * 16);
    y3[(R0 + 1) % 3] = *(const half8*)(yb + (R0 + 1) * Y_RS + g * 16);
    #pragma unroll
    for (int i = 0; i < NR; ++i) {
        const int r = R0 + i;
        y3[(r + 2) % 3] = *(const half8*)(yb + (r + 2) * Y_RS + g * 16);
        // acc-init = bn1 shifts
        f32x4 a0 = {shv0.x, shv0.y, shv0.z, shv0.w};
        f32x4 a1 = {shv1.x, shv1.y, shv1.z, shv1.w};
        #pragma unroll
        for (int s = 0; s < 3; ++s) {
            const half8 yy = y3[(r + s) % 3];
            a0 = __builtin_amdgcn_mfma_f32_16x16x32_f16(afA[s], yy, a0, 0,0,0);
            a1 = __builtin_amdgcn_mfma_f32_16x16x32_f16(afB[s], yy, a1, 0,0,0);
        }
        float z0[4], z1[4];
        #pragma unroll
        for (int r2 = 0; r2 < 4; ++r2) {
            z0[r2] = fmaxf(a0[r2], 0.01f * a0[r2]);
            z1[r2] = fmaxf(a1[r2], 0.01f * a1[r2]);
        }
        uint4 u;
        u.x = pkrtz(z0[0], z0[1]); u.y = pkrtz(z0[2], z0[3]);
        u.z = pkrtz(z1[0], z1[1]); u.w = pkrtz(z1[2], z1[3]);
        frH[i] = __builtin_bit_cast(half8, u);
    }
}

// ---- conv2 tile MT from prefolded fragments -> LDS out staging ----
template<int MT, int P0, int NP, int NR>
__device__ __forceinline__ void conv2_tile(
    float* __restrict__ sout, const half8 (&fr0)[NR], const half8 (&fr1)[NR],
    const int col, const int g, const int lane, const char* __restrict__ ws)
{
    const uint4* wf2 = (const uint4*)(ws + WF2_OFF);
    half8 af3[6];
    #pragma unroll
    for (int hh = 0; hh < 2; ++hh)
    #pragma unroll
    for (int tap = 0; tap < 3; ++tap)
        af3[tap*2 + hh] = __builtin_bit_cast(half8, wf2[((MT*2 + hh)*3 + tap)*64 + lane]);
    float4 shv = *(const float4*)((const float*)(ws + SH2_OFF) + g*8 + MT*4);

    #pragma unroll
    for (int pp = 0; pp < NP; ++pp) {
        const int p = P0 + pp;
        f32x4 acc = {shv.x, shv.y, shv.z, shv.w};   // acc-init = bn2 shifts
        #pragma unroll
        for (int s = 0; s < 6; ++s) {
            const half8 bb = (s & 1) ? fr1[pp + (s >> 1)] : fr0[pp + (s >> 1)];
            acc = __builtin_amdgcn_mfma_f32_16x16x32_f16(af3[s], bb, acc, 0,0,0);
        }
        #pragma unroll
        for (int r = 0; r < 4; ++r) {
            const int oc = MT*16 + 4*g + r;
            if (oc < 20) {
                float t0 = fmaxf(acc[r], 0.01f * acc[r]);
                sout[col*OUT_SDW + oc*11 + p] = t0;
            }
        }
    }
}

// ---- conv1 (two half-sweeps) -> fr regs -> conv2 (two tile-sweeps) -> LDS staging ----
template<int R0, int NR, int P0, int NP>
__device__ __forceinline__ void stack23(
    char* __restrict__ sxT, const int col, const int g, const int lane,
    const char* __restrict__ ws)
{
    float* sout = (float*)sxT;
    const char* yb = sxT + col * Y_BS;
    half8 fr0[NR], fr1[NR];
    conv1_half<0, R0, NR>(yb, fr0, lane, g, ws);
    __builtin_amdgcn_sched_barrier(0);    // keep the two halves' af live-ranges separate
    conv1_half<1, R0, NR>(yb, fr1, lane, g, ws);
    __syncthreads();   // all y reads done before out staging overwrites sxT
    conv2_tile<0, P0, NP, NR>(sout, fr0, fr1, col, g, lane, ws);
    __builtin_amdgcn_sched_barrier(0);
    conv2_tile<1, P0, NP, NR>(sout, fr0, fr1, col, g, lane, ws);
}

__global__ __launch_bounds__(THREADS, 2)
void peptide_v22(const float* __restrict__ x,
                 const char*  __restrict__ ws,     // prefolded fragments
                 float* __restrict__ out)          // [B][20][11]
{
    __shared__ __align__(16) char smem[SMEM_BYTES];
    char* sxT = smem;

    const int tid  = threadIdx.x;
    const int lane = tid & 63;
    const int wv   = tid >> 6;
    const int col  = lane & 15;
    const int g    = lane >> 4;

    // ---- quad-gather transpose: 192 tasks = (ch-group 0..2)*(p-quad 0..3)*(batch 0..15)
    {
        const float* xg = x + (size_t)blockIdx.x * (BPB * 315);
        #pragma unroll
        for (int q = 0; q < 2; ++q) {
            const int u = q * THREADS + tid;
            if (u < 192) {
                const int b2 = u & 15;
                const int qd = (u >> 4) & 3;
                const int ch = u >> 6;               // 0,1,2 (wave-uniform)
                const int po = (qd == 3) ? 11 : 4 * qd;
                const float* src = xg + b2 * 315 + po;
                char* dstb = sxT + b2 * Y_BS + ch * 16;
                if (ch < 2) {
                    f32x4 v4[8];
                    #pragma unroll
                    for (int j = 0; j < 8; ++j)
                        v4[j] = *(const f32x4*)(src + (ch * 8 + j) * 15);
                    #pragma unroll
                    for (int e = 0; e < 4; ++e) {
                        if (qd < 3 || e > 0) {
                            const int p = po + e;
                            uint4 d;
                            d.x = pkrtz(v4[0][e], v4[1][e]);
                            d.y = pkrtz(v4[2][e], v4[3][e]);
                            d.z = pkrtz(v4[4][e], v4[5][e]);
                            d.w = pkrtz(v4[6][e], v4[7][e]);
                            *(uint4*)(dstb + p * Y_RS) = d;
                        }
                    }
                } else {
                    f32x4 v4[5];
                    #pragma unroll
                    for (int j = 0; j < 5; ++j)
                        v4[j] = *(const f32x4*)(src + (16 + j) * 15);
                    const uint4 zz = {0u, 0u, 0u, 0u};
                    #pragma unroll
                    for (int e = 0; e < 4; ++e) {
                        if (qd < 3 || e > 0) {
                            const int p = po + e;
                            uint4 d;
                            d.x = pkrtz(v4[0][e], v4[1][e]);
                            d.y = pkrtz(v4[2][e], v4[3][e]);
                            d.z = pkrtz(v4[4][e], 0.f);
                            d.w = 0u;
                            *(uint4*)(dstb + p * Y_RS) = d;        // ch 16..23
                            *(uint4*)(dstb + p * Y_RS + 16) = zz;  // ch 24..31
                        }
                    }
                }
            }
        }
    }

    // fragments from d_ws
    half8 af0[2], af_att;
    float4 attb4;
    {
        const uint4* wf0 = (const uint4*)ws;
        af0[0] = __builtin_bit_cast(half8, wf0[lane]);
        af0[1] = __builtin_bit_cast(half8, wf0[64 + lane]);
        af_att = __builtin_bit_cast(half8, ((const uint4*)(ws + WFA_OFF))[lane]);
        attb4  = *(const float4*)((const float*)(ws + ATTB_OFF) + 4 * g);
    }
    __syncthreads();                      // xT ready

    // ---- conv0 MFMA + logit-MFMA + softmax (y in-place, logits in pads) ----
    if (wv == 0) conv0_att<0, 8>(sxT, af0, af_att, attb4, col, g, lane);
    else         conv0_att<8, 7>(sxT, af0, af_att, attb4, col, g, lane);
    __syncthreads();                      // y complete (cross-wave rows)

    // ---- conv1 -> regs -> conv2 -> out staging ----
    if (wv == 0) stack23<0, 8, 0, 6>(sxT, col, g, lane, ws);
    else         stack23<6, 7, 6, 5>(sxT, col, g, lane, ws);
    __syncthreads();                      // out staging complete

    // ---- gap-free coalesced copy-out: 16 x 220 dw = one 14080 B span ----
    {
        float* ob = out + (size_t)blockIdx.x * (BPB * 220);
        const float* sf = (const float*)sxT;
        #pragma unroll
        for (int j = 0; j < 7; ++j) {
            const int u = j * THREADS + tid;          // 16B unit
            if (u < 880) {
                f32x4 v = *(const f32x4*)(sf + u * 4);
                *(f32x4*)(ob + u * 4) = v;
            }
        }
    }
}

extern "C" void kernel_launch(void* const* d_in, const int* in_sizes, int n_in,
                              void* d_out, int out_size, void* d_ws, size_t ws_size,
                              hipStream_t stream) {
    const float* x    = (const float*)d_in[0];
    const float* w0   = (const float*)d_in[1];
    const float* attw = (const float*)d_in[2];
    const float* attb = (const float*)d_in[3];
    const float* w1   = (const float*)d_in[4];
    const float* cb1  = (const float*)d_in[5];
    const float* g1   = (const float*)d_in[6];
    const float* bt1  = (const float*)d_in[7];
    const float* mn1  = (const float*)d_in[8];
    const float* vr1  = (const float*)d_in[9];
    const float* w2   = (const float*)d_in[10];
    const float* cb2  = (const float*)d_in[11];
    const float* g2   = (const float*)d_in[12];
    const float* bt2  = (const float*)d_in[13];
    const float* mn2  = (const float*)d_in[14];
    const float* vr2  = (const float*)d_in[15];

    hipLaunchKernelGGL(peptide_prep, dim3(1), dim3(256), 0, stream,
                       w0, attw, attb, w1, cb1, g1, bt1, mn1, vr1,
                       w2, cb2, g2, bt2, mn2, vr2, (char*)d_ws);
    hipLaunchKernelGGL(peptide_v22, dim3(NBLOCKS), dim3(THREADS), 0, stream,
                       x, (const char*)d_ws, (float*)d_out);
}